// Round 20
// baseline (300.215 us; speedup 1.0000x reference)
//
#include <hip/hip_runtime.h>

typedef short short8 __attribute__((ext_vector_type(8)));
typedef float f32x4 __attribute__((ext_vector_type(4)));
typedef float f32x16 __attribute__((ext_vector_type(16)));
typedef unsigned short u16;
typedef u16 u16x8 __attribute__((ext_vector_type(8)));
typedef unsigned int u32;
typedef u32 u32x4 __attribute__((ext_vector_type(4)));

#define NTOK 4096
#define CDIM 256
#define TJ 64
#define NJT 16              // j-tiles per block (1024 keys / 64)
#define LOG2E 1.44269504088896f

__device__ __forceinline__ u16 f2bf(float f) {
    unsigned u = __float_as_uint(f);
    unsigned r = (u + 0x7fffu + ((u >> 16) & 1u)) >> 16;   // RNE
    return (u16)r;
}
__device__ __forceinline__ float bf2f(u16 h) { return __uint_as_float(((unsigned)h) << 16); }
__device__ __forceinline__ u32 pk_bf16(float a, float b) {
    u32 w;
    asm("v_cvt_pk_bf16_f32 %0, %1, %2" : "=v"(w) : "v"(a), "v"(b));
    return w;
}

// ---------------------------------------------------------------------------
// W convert: rows 0-31 Wq (pre-scaled by LOG2E), 32-63 Wk, 64-319 Wv
// ---------------------------------------------------------------------------
__global__ __launch_bounds__(256)
void wconv(const float* __restrict__ Wq, const float* __restrict__ Wk,
           const float* __restrict__ Wv, u16* __restrict__ whi, u16* __restrict__ wlo) {
    const int row = blockIdx.x;
    const int col = threadIdx.x;
    float v;
    if (row < 32)       v = Wq[row * 256 + col] * LOG2E;
    else if (row < 64)  v = Wk[(row - 32) * 256 + col];
    else                v = Wv[(row - 64) * 256 + col];
    u16 h = f2bf(v);
    whi[row * 256 + col] = h;
    wlo[row * 256 + col] = f2bf(v - bf2f(h));
}

// ---------------------------------------------------------------------------
// Fused projection via MFMA (hi/lo 3-term). (verified r5-r19, unchanged)
// ---------------------------------------------------------------------------
__global__ __launch_bounds__(256, 1)
void proj_fused(const float* __restrict__ x,
                const u16* __restrict__ whi, const u16* __restrict__ wlo,
                const float* __restrict__ bq, const float* __restrict__ bk,
                const float* __restrict__ bv,
                u16* __restrict__ qhi, u16* __restrict__ qlo,
                u16* __restrict__ khi, u16* __restrict__ klo,
                u16* __restrict__ vbf) {
    __shared__ __attribute__((aligned(16))) u16 lxh[64][260];
    __shared__ __attribute__((aligned(16))) u16 lxl[64][260];
    const int b  = blockIdx.y;
    const int n0 = blockIdx.x * 64;
    const int t  = threadIdx.x;
    const int w  = t >> 6;
    const int l  = t & 63;
    const int cl = l & 15;
    const int kg = l >> 4;

    const int sn = (t & 15) * 4;
    const int sc = t >> 4;
#pragma unroll
    for (int cc = 0; cc < 16; cc++) {
        const int c = sc + cc * 16;
        const f32x4 xv = *(const f32x4*)&x[((size_t)(b * CDIM + c)) * NTOK + n0 + sn];
#pragma unroll
        for (int i = 0; i < 4; i++) {
            u16 hh = f2bf(xv[i]);
            lxh[sn + i][c] = hh;
            lxl[sn + i][c] = f2bf(xv[i] - bf2f(hh));
        }
    }
    __syncthreads();

    f32x4 acc[5][4];
    const f32x4 fz = {0.f, 0.f, 0.f, 0.f};
#pragma unroll
    for (int i = 0; i < 5; i++)
#pragma unroll
        for (int nt = 0; nt < 4; nt++) acc[i][nt] = fz;

#pragma unroll 2
    for (int ks = 0; ks < 8; ks++) {
        const int k0 = ks * 32;
        short8 bh[4], bl[4];
#pragma unroll
        for (int nt = 0; nt < 4; nt++) {
            bh[nt] = *(const short8*)&lxh[nt * 16 + cl][k0 + kg * 8];
            bl[nt] = *(const short8*)&lxl[nt * 16 + cl][k0 + kg * 8];
        }
#pragma unroll
        for (int i = 0; i < 5; i++) {
            const int mt = w * 5 + i;
            const size_t wb = (size_t)(mt * 16 + cl) * 256 + k0 + kg * 8;
            const short8 ah = *(const short8*)&whi[wb];
            const short8 al = *(const short8*)&wlo[wb];
#pragma unroll
            for (int nt = 0; nt < 4; nt++) {
                acc[i][nt] = __builtin_amdgcn_mfma_f32_16x16x32_bf16(ah, bh[nt], acc[i][nt], 0, 0, 0);
                acc[i][nt] = __builtin_amdgcn_mfma_f32_16x16x32_bf16(ah, bl[nt], acc[i][nt], 0, 0, 0);
                acc[i][nt] = __builtin_amdgcn_mfma_f32_16x16x32_bf16(al, bh[nt], acc[i][nt], 0, 0, 0);
            }
        }
    }

#pragma unroll
    for (int i = 0; i < 5; i++) {
        const int mt = w * 5 + i;
#pragma unroll
        for (int nt = 0; nt < 4; nt++) {
            const int n = n0 + nt * 16 + cl;
#pragma unroll
            for (int r = 0; r < 4; r++) {
                const int m = kg * 4 + r;
                float v = acc[i][nt][r];
                if (mt < 2) {
                    const int ch = mt * 16 + m;
                    v += bq[ch] * LOG2E;
                    u16 hh = f2bf(v);
                    qhi[((size_t)(b * NTOK + n)) * 32 + ch] = hh;
                    qlo[((size_t)(b * NTOK + n)) * 32 + ch] = f2bf(v - bf2f(hh));
                } else if (mt < 4) {
                    const int ch = (mt - 2) * 16 + m;
                    v += bk[ch];
                    u16 hh = f2bf(v);
                    khi[((size_t)(b * NTOK + n)) * 32 + ch] = hh;
                    klo[((size_t)(b * NTOK + n)) * 32 + ch] = f2bf(v - bf2f(hh));
                } else {
                    const int c2 = (mt - 4) * 16 + m;
                    vbf[((size_t)(b * CDIM + c2)) * NTOK + n] = f2bf(v + bv[c2]);
                }
            }
        }
    }
}

// ---------------------------------------------------------------------------
// Flash attention partials. Round 20: each wave handles TWO 32-q subtiles so
// every K/V ds_read feeds two MFMAs (per-q LDS ops halved; LDS pipe was the
// measured saturated resource). 4-way j-split, NJT=16, grid 512, m=0 fixed.
// ---------------------------------------------------------------------------
__global__ __launch_bounds__(256, 2)
void attn_part(const u16* __restrict__ qhi, const u16* __restrict__ qlo,
               const u16* __restrict__ khi, const u16* __restrict__ klo,
               const u16* __restrict__ vbf,
               u16* __restrict__ pacc, float* __restrict__ pl) {
    __shared__ __attribute__((aligned(16))) u16 lkh[2][TJ][32];
    __shared__ __attribute__((aligned(16))) u16 lkl[2][TJ][32];
    __shared__ __attribute__((aligned(16))) u16 lv[2][128][72];
    // lt aliased onto lv: epilogue-only; lt[w] wave-private.
    float (*lt)[32][33] = reinterpret_cast<float (*)[32][33]>(&lv[0][0][0]);

    const int lin = blockIdx.x;
    const int p   = lin & 7;        // (b,h) fixed per XCD
    const int b   = p >> 1;
    const int h   = p & 1;
    const int js  = (lin >> 3) & 3;
    const int qp  = lin >> 5;       // 0..15
    const int i0  = qp * 256;
    const int jb  = js * 1024;
    const int t   = threadIdx.x;
    const int w   = t >> 6;
    const int l   = t & 63;
    const int q5  = l & 31;
    const int hi  = l >> 5;

    // Q B-fragments for two subtiles (r11-verified layout)
    const int iqA = i0 + w * 64 + q5;
    const size_t qbA = ((size_t)(b * NTOK + iqA)) * 32;
    const size_t qbB = qbA + 32 * 32;           // +32 tokens
    const short8 qAh0 = *(const short8*)&qhi[qbA + hi * 8];
    const short8 qAh1 = *(const short8*)&qhi[qbA + 16 + hi * 8];
    const short8 qAl0 = *(const short8*)&qlo[qbA + hi * 8];
    const short8 qAl1 = *(const short8*)&qlo[qbA + 16 + hi * 8];
    const short8 qBh0 = *(const short8*)&qhi[qbB + hi * 8];
    const short8 qBh1 = *(const short8*)&qhi[qbB + 16 + hi * 8];
    const short8 qBl0 = *(const short8*)&qlo[qbB + hi * 8];
    const short8 qBl1 = *(const short8*)&qlo[qbB + 16 + hi * 8];

    // V staging: 128 rows x 64 j, 4 chunks/thread (r11-verified swizzle)
    const int vc   = t & 127;
    const int vch0 = (t >> 7) * 4;
    const u16* vsrc = &vbf[((size_t)(b * CDIM + h * 128 + vc)) * NTOK];
    // K staging: 64 rows x 32 d hi/lo, 2 chunks/thread (r7/r9-verified)
    const int kj   = (t & 127) >> 1;
    const int kch2 = (t & 1) * 2;
    const u16* ksrcbase = (t < 128) ? khi : klo;
    const u16* ksrc = &ksrcbase[((size_t)(b * NTOK + kj)) * 32 + kch2 * 8];

    u16x8 vreg[4];
    u16x8 kreg0, kreg1;

    auto stage_load = [&](int tt) {
        const size_t j0 = (size_t)(jb + tt * TJ);
#pragma unroll
        for (int i = 0; i < 4; i++)
            vreg[i] = *(const u16x8*)&vsrc[j0 + (vch0 + i) * 8];
        kreg0 = *(const u16x8*)&ksrc[j0 * 32];
        kreg1 = *(const u16x8*)&ksrc[j0 * 32 + 8];
    };
    auto stage_write = [&](int buf) {
        const int s2 = (vc >> 2) & 3;
#pragma unroll
        for (int i = 0; i < 4; i++) {
            const int ci = vch0 + i;
            const int ps = (ci & 4) | ((ci ^ s2) & 3);
            *(u16x8*)&lv[buf][vc][ps * 8] = vreg[i];
        }
        const int swk = (kj >> 2) & 3;
        u16* kbase = (t < 128) ? &lkh[buf][kj][0] : &lkl[buf][kj][0];
        *(u16x8*)&kbase[((kch2)     ^ swk) * 8] = kreg0;
        *(u16x8*)&kbase[((kch2 + 1) ^ swk) * 8] = kreg1;
    };

    f32x16 accA0, accA1, accA2, accA3;   // subtile A, c-tiles 0..3
    f32x16 accB0, accB1, accB2, accB3;   // subtile B
#pragma unroll
    for (int i = 0; i < 16; i++) {
        accA0[i] = 0.f; accA1[i] = 0.f; accA2[i] = 0.f; accA3[i] = 0.f;
        accB0[i] = 0.f; accB1[i] = 0.f; accB2[i] = 0.f; accB3[i] = 0.f;
    }
    float l_rA = 0.f, l_rB = 0.f;

    // in-register P -> B-frag exchange (r11-verified)
    auto mkfrag = [&](u32 own0, u32 own1, u32 own2, u32 own3) -> short8 {
        const u32 sendA = hi ? own0 : own2;
        const u32 sendB = hi ? own1 : own3;
        const u32 recvA = (u32)__shfl_xor((int)sendA, 32);
        const u32 recvB = (u32)__shfl_xor((int)sendB, 32);
        u32x4 bw;
        bw[0] = hi ? recvA : own0;
        bw[1] = hi ? recvB : own1;
        bw[2] = hi ? own2 : recvA;
        bw[3] = hi ? own3 : recvB;
        return __builtin_bit_cast(short8, bw);
    };

    stage_load(0);
    stage_write(0);
    __syncthreads();

#pragma unroll 2
    for (int tt = 0; tt < NJT; ++tt) {
        const int cur = tt & 1;
        const int nxt = cur ^ 1;
        const bool pre = (tt + 1 < NJT);
        if (pre) stage_load(tt + 1);    // issue global loads early (T14)

#pragma unroll
        for (int jt = 0; jt < 2; jt++) {
            // ---- shared K reads (4 b128), 12 QK^T mfma (6 per subtile) ----
            const int row = jt * 32 + q5;
            const int sw  = (row >> 2) & 3;
            const int ph0 = ((hi) ^ sw) * 8;        // dhalf 0
            const int ph1 = ((2 + hi) ^ sw) * 8;    // dhalf 1
            const short8 kh0 = *(const short8*)&lkh[cur][row][ph0];
            const short8 kl0 = *(const short8*)&lkl[cur][row][ph0];
            const short8 kh1 = *(const short8*)&lkh[cur][row][ph1];
            const short8 kl1 = *(const short8*)&lkl[cur][row][ph1];

            f32x16 sA, sB;
#pragma unroll
            for (int i = 0; i < 16; i++) { sA[i] = 0.f; sB[i] = 0.f; }
            __builtin_amdgcn_s_setprio(1);
            sA = __builtin_amdgcn_mfma_f32_32x32x16_bf16(kh0, qAh0, sA, 0, 0, 0);
            sA = __builtin_amdgcn_mfma_f32_32x32x16_bf16(kl0, qAh0, sA, 0, 0, 0);
            sA = __builtin_amdgcn_mfma_f32_32x32x16_bf16(kh0, qAl0, sA, 0, 0, 0);
            sA = __builtin_amdgcn_mfma_f32_32x32x16_bf16(kh1, qAh1, sA, 0, 0, 0);
            sA = __builtin_amdgcn_mfma_f32_32x32x16_bf16(kl1, qAh1, sA, 0, 0, 0);
            sA = __builtin_amdgcn_mfma_f32_32x32x16_bf16(kh1, qAl1, sA, 0, 0, 0);
            sB = __builtin_amdgcn_mfma_f32_32x32x16_bf16(kh0, qBh0, sB, 0, 0, 0);
            sB = __builtin_amdgcn_mfma_f32_32x32x16_bf16(kl0, qBh0, sB, 0, 0, 0);
            sB = __builtin_amdgcn_mfma_f32_32x32x16_bf16(kh0, qBl0, sB, 0, 0, 0);
            sB = __builtin_amdgcn_mfma_f32_32x32x16_bf16(kh1, qBh1, sB, 0, 0, 0);
            sB = __builtin_amdgcn_mfma_f32_32x32x16_bf16(kl1, qBh1, sB, 0, 0, 0);
            sB = __builtin_amdgcn_mfma_f32_32x32x16_bf16(kh1, qBl1, sB, 0, 0, 0);
            __builtin_amdgcn_s_setprio(0);

            // ---- exp (scores pre-scaled by log2e), l partials ----
#pragma unroll
            for (int i = 0; i < 16; i++) {
                sA[i] = exp2f(sA[i]);
                sB[i] = exp2f(sB[i]);
            }
            float psA = 0.f, psB = 0.f;
#pragma unroll
            for (int i = 0; i < 16; i++) { psA += sA[i]; psB += sB[i]; }
            l_rA += psA;
            l_rB += psB;

            short8 pfA0 = mkfrag(pk_bf16(sA[0],  sA[1]),  pk_bf16(sA[2],  sA[3]),
                                 pk_bf16(sA[4],  sA[5]),  pk_bf16(sA[6],  sA[7]));
            short8 pfA1 = mkfrag(pk_bf16(sA[8],  sA[9]),  pk_bf16(sA[10], sA[11]),
                                 pk_bf16(sA[12], sA[13]), pk_bf16(sA[14], sA[15]));
            short8 pfB0 = mkfrag(pk_bf16(sB[0],  sB[1]),  pk_bf16(sB[2],  sB[3]),
                                 pk_bf16(sB[4],  sB[5]),  pk_bf16(sB[6],  sB[7]));
            short8 pfB1 = mkfrag(pk_bf16(sB[8],  sB[9]),  pk_bf16(sB[10], sB[11]),
                                 pk_bf16(sB[12], sB[13]), pk_bf16(sB[14], sB[15]));

            // ---- PV: 8 shared V reads, 16 mfma (each vb feeds A and B) ----
            __builtin_amdgcn_s_setprio(1);
#pragma unroll
            for (int jgl = 0; jgl < 2; jgl++) {
                const int ch = (jt * 2 + jgl) * 2 + hi;
                const short8 pfA = jgl ? pfA1 : pfA0;
                const short8 pfB = jgl ? pfB1 : pfB0;
#define PV_CT(CT, ACCA, ACCB)                                                 \
                {                                                             \
                    const int vrow = CT * 32 + q5;                            \
                    const int vsw  = (vrow >> 2) & 3;                         \
                    const int vph  = ((ch & 4) | ((ch ^ vsw) & 3)) * 8;       \
                    short8 vb = *(const short8*)&lv[cur][vrow][vph];          \
                    ACCA = __builtin_amdgcn_mfma_f32_32x32x16_bf16(vb, pfA, ACCA, 0, 0, 0); \
                    ACCB = __builtin_amdgcn_mfma_f32_32x32x16_bf16(vb, pfB, ACCB, 0, 0, 0); \
                }
                PV_CT(0, accA0, accB0)
                PV_CT(1, accA1, accB1)
                PV_CT(2, accA2, accB2)
                PV_CT(3, accA3, accB3)
#undef PV_CT
            }
            __builtin_amdgcn_s_setprio(0);
        }

        if (pre) stage_write(nxt);
        __syncthreads();
    }
    // lv dead after final barrier; lt (aliased) safe.

    // ---- l: reduce over hi halves, store (h==0 blocks only) ----
    l_rA += __shfl_xor(l_rA, 32);
    l_rB += __shfl_xor(l_rB, 32);
    if (h == 0 && l < 32) {
        const size_t plb = (size_t)(b * 4 + js) * NTOK + i0 + w * 64;
        pl[plb + q5]      = l_rA;
        pl[plb + 32 + q5] = l_rB;
    }

    // ---- write partial acc as bf16 via per-wave lt transpose ----
    const size_t tile = (size_t)(((b * 2 + h) * 4 + js) * 16 + qp);
    const int r2 = l >> 1;
    const int qc = (l & 1) * 16;
#pragma unroll
    for (int sub = 0; sub < 2; sub++) {
#pragma unroll
        for (int ct = 0; ct < 4; ct++) {
            const f32x16 a =
                (sub == 0)
                    ? ((ct == 0) ? accA0 : (ct == 1) ? accA1 : (ct == 2) ? accA2 : accA3)
                    : ((ct == 0) ? accB0 : (ct == 1) ? accB1 : (ct == 2) ? accB2 : accB3);
#pragma unroll
            for (int reg = 0; reg < 16; reg++) {
                const int crow = (reg & 3) + 8 * (reg >> 2) + 4 * hi;
                lt[w][crow][q5] = a[reg];
            }
            // lt[w] wave-private; DS ops in-order per wave
            const int c_local = ct * 32 + r2;
            const size_t base = (tile * 128 + c_local) * 256 + w * 64 + sub * 32 + qc;
            u32x4 pk0, pk1;
#pragma unroll
            for (int i = 0; i < 4; i++)
                pk0[i] = pk_bf16(lt[w][r2][qc + 2 * i], lt[w][r2][qc + 2 * i + 1]);
#pragma unroll
            for (int i = 0; i < 4; i++)
                pk1[i] = pk_bf16(lt[w][r2][qc + 8 + 2 * i], lt[w][r2][qc + 8 + 2 * i + 1]);
            *(u32x4*)&pacc[base]     = pk0;
            *(u32x4*)&pacc[base + 8] = pk1;
        }
    }
}

// ---------------------------------------------------------------------------
// Combine: out = (sum_js acc) / (sum_js l) + x.  bf16 pacc, 256-q tiles.
// ---------------------------------------------------------------------------
__global__ __launch_bounds__(256)
void attn_combine(const u16* __restrict__ pacc, const float* __restrict__ pl,
                  const float* __restrict__ x, float* __restrict__ out) {
    const int g = blockIdx.x * 256 + threadIdx.x;     // grid 512 -> 131072 thr
#pragma unroll
    for (int rep = 0; rep < 4; rep++) {
        const int f = g + rep * 131072;               // 8-q unit, 0..524287
        const int il8 = f & 31;                       // q-octet within 256
        const int qp  = (f >> 5) & 15;
        const int c   = (f >> 9) & 255;
        const int b   = f >> 17;
        const int h   = c >> 7;
        const int cl7 = c & 127;
        f32x4 as0 = {0.f, 0.f, 0.f, 0.f};
        f32x4 as1 = {0.f, 0.f, 0.f, 0.f};
        f32x4 ls0 = {0.f, 0.f, 0.f, 0.f};
        f32x4 ls1 = {0.f, 0.f, 0.f, 0.f};
#pragma unroll
        for (int js = 0; js < 4; js++) {
            const size_t tile = (size_t)(((b * 2 + h) * 4 + js) * 16 + qp);
            const u16x8 a = *(const u16x8*)&pacc[(tile * 128 + cl7) * 256 + il8 * 8];
            const size_t lb = (size_t)(b * 4 + js) * 4096 + qp * 256 + il8 * 8;
            const f32x4 l0 = *(const f32x4*)&pl[lb];
            const f32x4 l1 = *(const f32x4*)&pl[lb + 4];
#pragma unroll
            for (int i = 0; i < 4; i++) {
                as0[i] += bf2f(a[i]);
                as1[i] += bf2f(a[4 + i]);
                ls0[i] += l0[i];
                ls1[i] += l1[i];
            }
        }
        const size_t ox = ((size_t)(b * 256 + c)) * 4096 + qp * 256 + il8 * 8;
        const f32x4 x0 = *(const f32x4*)&x[ox];
        const f32x4 x1 = *(const f32x4*)&x[ox + 4];
        f32x4 o0, o1;
#pragma unroll
        for (int i = 0; i < 4; i++) {
            o0[i] = as0[i] / ls0[i] + x0[i];
            o1[i] = as1[i] / ls1[i] + x1[i];
        }
        *(f32x4*)&out[ox]     = o0;
        *(f32x4*)&out[ox + 4] = o1;
    }
}

// ---------------------------------------------------------------------------
extern "C" void kernel_launch(void* const* d_in, const int* in_sizes, int n_in,
                              void* d_out, int out_size, void* d_ws, size_t ws_size,
                              hipStream_t stream) {
    const float* x  = (const float*)d_in[0];
    const float* Wq = (const float*)d_in[1];
    const float* bq = (const float*)d_in[2];
    const float* Wk = (const float*)d_in[3];
    const float* bk = (const float*)d_in[4];
    const float* Wv = (const float*)d_in[5];
    const float* bv = (const float*)d_in[6];
    float* out = (float*)d_out;

    u16* qhi = (u16*)d_ws;                              // [4][4096][32]
    u16* qlo = qhi + (size_t)4 * NTOK * 32;
    u16* khi = qlo + (size_t)4 * NTOK * 32;
    u16* klo = khi + (size_t)4 * NTOK * 32;
    u16* vbf = klo + (size_t)4 * NTOK * 32;             // [4][256][4096]
    u16* whi = vbf + (size_t)4 * CDIM * NTOK;           // [320][256]
    u16* wlo = whi + (size_t)320 * 256;
    u16* pacc = wlo + (size_t)320 * 256;                // [512][128][256] bf16
    float* pl = (float*)(pacc + (size_t)512 * 128 * 256);  // [16][4096] f32

    wconv<<<dim3(320), 256, 0, stream>>>(Wq, Wk, Wv, whi, wlo);
    proj_fused<<<dim3(64, 4), 256, 0, stream>>>(x, whi, wlo, bq, bk, bv,
                                                qhi, qlo, khi, klo, vbf);
    attn_part<<<dim3(512), 256, 0, stream>>>(qhi, qlo, khi, klo, vbf, pacc, pl);
    attn_combine<<<dim3(512), 256, 0, stream>>>(pacc, pl, x, out);
}

// Round 21
// 126.557 us; speedup vs baseline: 2.3722x; 2.3722x over previous
//
#include <hip/hip_runtime.h>

typedef short short8 __attribute__((ext_vector_type(8)));
typedef float f32x4 __attribute__((ext_vector_type(4)));
typedef float f32x16 __attribute__((ext_vector_type(16)));
typedef unsigned short u16;
typedef u16 u16x8 __attribute__((ext_vector_type(8)));
typedef unsigned int u32;
typedef u32 u32x4 __attribute__((ext_vector_type(4)));

#define NTOK 4096
#define CDIM 256
#define TJ 64
#define NJT 32              // j-tiles per block (2048 keys / 64)
#define LOG2E 1.44269504088896f

__device__ __forceinline__ u16 f2bf(float f) {
    unsigned u = __float_as_uint(f);
    unsigned r = (u + 0x7fffu + ((u >> 16) & 1u)) >> 16;   // RNE
    return (u16)r;
}
__device__ __forceinline__ float bf2f(u16 h) { return __uint_as_float(((unsigned)h) << 16); }
__device__ __forceinline__ u32 pk_bf16(float a, float b) {
    u32 w;
    asm("v_cvt_pk_bf16_f32 %0, %1, %2" : "=v"(w) : "v"(a), "v"(b));
    return w;
}

// ---------------------------------------------------------------------------
// W convert: rows 0-31 Wq (pre-scaled by LOG2E so QK^T yields s*log2e),
// 32-63 Wk, 64-319 Wv -> whi/wlo bf16 [320][256]
// ---------------------------------------------------------------------------
__global__ __launch_bounds__(256)
void wconv(const float* __restrict__ Wq, const float* __restrict__ Wk,
           const float* __restrict__ Wv, u16* __restrict__ whi, u16* __restrict__ wlo) {
    const int row = blockIdx.x;
    const int col = threadIdx.x;
    float v;
    if (row < 32)       v = Wq[row * 256 + col] * LOG2E;
    else if (row < 64)  v = Wk[(row - 32) * 256 + col];
    else                v = Wv[(row - 64) * 256 + col];
    u16 h = f2bf(v);
    whi[row * 256 + col] = h;
    wlo[row * 256 + col] = f2bf(v - bf2f(h));
}

// ---------------------------------------------------------------------------
// Fused projection via MFMA (hi/lo 3-term). Block: 64 tokens, all 320 out ch.
// Q bias scaled by LOG2E to match the pre-scaled Wq.
// ---------------------------------------------------------------------------
__global__ __launch_bounds__(256, 1)
void proj_fused(const float* __restrict__ x,
                const u16* __restrict__ whi, const u16* __restrict__ wlo,
                const float* __restrict__ bq, const float* __restrict__ bk,
                const float* __restrict__ bv,
                u16* __restrict__ qhi, u16* __restrict__ qlo,
                u16* __restrict__ khi, u16* __restrict__ klo,
                u16* __restrict__ vbf) {
    __shared__ __attribute__((aligned(16))) u16 lxh[64][260];
    __shared__ __attribute__((aligned(16))) u16 lxl[64][260];
    const int b  = blockIdx.y;
    const int n0 = blockIdx.x * 64;
    const int t  = threadIdx.x;
    const int w  = t >> 6;
    const int l  = t & 63;
    const int cl = l & 15;
    const int kg = l >> 4;

    const int sn = (t & 15) * 4;
    const int sc = t >> 4;
#pragma unroll
    for (int cc = 0; cc < 16; cc++) {
        const int c = sc + cc * 16;
        const f32x4 xv = *(const f32x4*)&x[((size_t)(b * CDIM + c)) * NTOK + n0 + sn];
#pragma unroll
        for (int i = 0; i < 4; i++) {
            u16 hh = f2bf(xv[i]);
            lxh[sn + i][c] = hh;
            lxl[sn + i][c] = f2bf(xv[i] - bf2f(hh));
        }
    }
    __syncthreads();

    f32x4 acc[5][4];
    const f32x4 fz = {0.f, 0.f, 0.f, 0.f};
#pragma unroll
    for (int i = 0; i < 5; i++)
#pragma unroll
        for (int nt = 0; nt < 4; nt++) acc[i][nt] = fz;

#pragma unroll 2
    for (int ks = 0; ks < 8; ks++) {
        const int k0 = ks * 32;
        short8 bh[4], bl[4];
#pragma unroll
        for (int nt = 0; nt < 4; nt++) {
            bh[nt] = *(const short8*)&lxh[nt * 16 + cl][k0 + kg * 8];
            bl[nt] = *(const short8*)&lxl[nt * 16 + cl][k0 + kg * 8];
        }
#pragma unroll
        for (int i = 0; i < 5; i++) {
            const int mt = w * 5 + i;
            const size_t wb = (size_t)(mt * 16 + cl) * 256 + k0 + kg * 8;
            const short8 ah = *(const short8*)&whi[wb];
            const short8 al = *(const short8*)&wlo[wb];
#pragma unroll
            for (int nt = 0; nt < 4; nt++) {
                acc[i][nt] = __builtin_amdgcn_mfma_f32_16x16x32_bf16(ah, bh[nt], acc[i][nt], 0, 0, 0);
                acc[i][nt] = __builtin_amdgcn_mfma_f32_16x16x32_bf16(ah, bl[nt], acc[i][nt], 0, 0, 0);
                acc[i][nt] = __builtin_amdgcn_mfma_f32_16x16x32_bf16(al, bh[nt], acc[i][nt], 0, 0, 0);
            }
        }
    }

#pragma unroll
    for (int i = 0; i < 5; i++) {
        const int mt = w * 5 + i;
#pragma unroll
        for (int nt = 0; nt < 4; nt++) {
            const int n = n0 + nt * 16 + cl;
#pragma unroll
            for (int r = 0; r < 4; r++) {
                const int m = kg * 4 + r;
                float v = acc[i][nt][r];
                if (mt < 2) {
                    const int ch = mt * 16 + m;
                    v += bq[ch] * LOG2E;
                    u16 hh = f2bf(v);
                    qhi[((size_t)(b * NTOK + n)) * 32 + ch] = hh;
                    qlo[((size_t)(b * NTOK + n)) * 32 + ch] = f2bf(v - bf2f(hh));
                } else if (mt < 4) {
                    const int ch = (mt - 2) * 16 + m;
                    v += bk[ch];
                    u16 hh = f2bf(v);
                    khi[((size_t)(b * NTOK + n)) * 32 + ch] = hh;
                    klo[((size_t)(b * NTOK + n)) * 32 + ch] = f2bf(v - bf2f(hh));
                } else {
                    const int c2 = (mt - 4) * 16 + m;
                    vbf[((size_t)(b * CDIM + c2)) * NTOK + n] = f2bf(v + bv[c2]);
                }
            }
        }
    }
}

// ---------------------------------------------------------------------------
// Flash attention partials, 32x32 MFMA, j-split 2-way, fixed m=0.
// (measured-best r19 configuration: TJ=64, grid 512, bf16 partials,
//  scores pre-scaled by log2e, lt aliased onto lv)
// ---------------------------------------------------------------------------
__global__ __launch_bounds__(256, 2)
void attn_part(const u16* __restrict__ qhi, const u16* __restrict__ qlo,
               const u16* __restrict__ khi, const u16* __restrict__ klo,
               const u16* __restrict__ vbf,
               u16* __restrict__ pacc, float* __restrict__ pl) {
    __shared__ __attribute__((aligned(16))) u16 lkh[2][TJ][32];
    __shared__ __attribute__((aligned(16))) u16 lkl[2][TJ][32];
    __shared__ __attribute__((aligned(16))) u16 lv[2][128][72];
    // lt[4][32][33] f32 aliased onto lv: epilogue-only (lv dead after final
    // barrier); lt[w] wave-private.
    float (*lt)[32][33] = reinterpret_cast<float (*)[32][33]>(&lv[0][0][0]);

    const int lin = blockIdx.x;
    const int p   = lin & 7;        // XCD: fixed (b,h) -> K[b]+V-half in L2
    const int b   = p >> 1;
    const int h   = p & 1;
    const int js  = (lin >> 3) & 1;
    const int qb  = lin >> 4;       // 0..31
    const int i0  = qb * 128;
    const int jb  = js * 2048;
    const int t   = threadIdx.x;
    const int w   = t >> 6;
    const int l   = t & 63;
    const int q5  = l & 31;
    const int hi  = l >> 5;

    // Q B-fragments (r11-verified)
    const int iq = i0 + w * 32 + q5;
    const size_t qbase = ((size_t)(b * NTOK + iq)) * 32;
    const short8 qh0 = *(const short8*)&qhi[qbase + hi * 8];
    const short8 qh1 = *(const short8*)&qhi[qbase + 16 + hi * 8];
    const short8 ql0 = *(const short8*)&qlo[qbase + hi * 8];
    const short8 ql1 = *(const short8*)&qlo[qbase + 16 + hi * 8];

    // V staging: 128 rows x 64 j, 4 chunks/thread (r11-verified swizzle)
    const int vc   = t & 127;
    const int vch0 = (t >> 7) * 4;
    const u16* vsrc = &vbf[((size_t)(b * CDIM + h * 128 + vc)) * NTOK];
    // K staging: 64 rows x 32 d hi/lo, 2 chunks/thread (r7/r9-verified)
    const int kj   = (t & 127) >> 1;
    const int kch2 = (t & 1) * 2;
    const u16* ksrcbase = (t < 128) ? khi : klo;
    const u16* ksrc = &ksrcbase[((size_t)(b * NTOK + kj)) * 32 + kch2 * 8];

    u16x8 vreg[4];
    u16x8 kreg0, kreg1;

    auto stage_load = [&](int tt) {
        const size_t j0 = (size_t)(jb + tt * TJ);
#pragma unroll
        for (int i = 0; i < 4; i++)
            vreg[i] = *(const u16x8*)&vsrc[j0 + (vch0 + i) * 8];
        kreg0 = *(const u16x8*)&ksrc[j0 * 32];
        kreg1 = *(const u16x8*)&ksrc[j0 * 32 + 8];
    };
    auto stage_write = [&](int buf) {
        const int s2 = (vc >> 2) & 3;
#pragma unroll
        for (int i = 0; i < 4; i++) {
            const int ci = vch0 + i;
            const int ps = (ci & 4) | ((ci ^ s2) & 3);
            *(u16x8*)&lv[buf][vc][ps * 8] = vreg[i];
        }
        const int swk = (kj >> 2) & 3;
        u16* kbase = (t < 128) ? &lkh[buf][kj][0] : &lkl[buf][kj][0];
        *(u16x8*)&kbase[((kch2)     ^ swk) * 8] = kreg0;
        *(u16x8*)&kbase[((kch2 + 1) ^ swk) * 8] = kreg1;
    };

    f32x16 acc0, acc1, acc2, acc3;    // c-tiles 0..3 (32 c each), q = q5
#pragma unroll
    for (int i = 0; i < 16; i++) { acc0[i] = 0.f; acc1[i] = 0.f; acc2[i] = 0.f; acc3[i] = 0.f; }
    float l_r = 0.f;

    // ---- QK^T for one 32-j tile (6 mfma32, 3-term hi/lo) — r11-verified ----
    auto qkt32 = [&](int cur, int jt) -> f32x16 {
        f32x16 s;
#pragma unroll
        for (int i = 0; i < 16; i++) s[i] = 0.f;
        const int row = jt * 32 + q5;
        const int sw  = (row >> 2) & 3;
        {
            const int ph = ((0 * 2 + hi) ^ sw) * 8;
            short8 kh = *(const short8*)&lkh[cur][row][ph];
            short8 kl = *(const short8*)&lkl[cur][row][ph];
            s = __builtin_amdgcn_mfma_f32_32x32x16_bf16(kh, qh0, s, 0, 0, 0);
            s = __builtin_amdgcn_mfma_f32_32x32x16_bf16(kl, qh0, s, 0, 0, 0);
            s = __builtin_amdgcn_mfma_f32_32x32x16_bf16(kh, ql0, s, 0, 0, 0);
        }
        {
            const int ph = ((1 * 2 + hi) ^ sw) * 8;
            short8 kh = *(const short8*)&lkh[cur][row][ph];
            short8 kl = *(const short8*)&lkl[cur][row][ph];
            s = __builtin_amdgcn_mfma_f32_32x32x16_bf16(kh, qh1, s, 0, 0, 0);
            s = __builtin_amdgcn_mfma_f32_32x32x16_bf16(kl, qh1, s, 0, 0, 0);
            s = __builtin_amdgcn_mfma_f32_32x32x16_bf16(kh, ql1, s, 0, 0, 0);
        }
        return s;
    };

    // ---- in-register P -> B-frag exchange (r11-verified) ----
    auto mkfrag = [&](u32 own0, u32 own1, u32 own2, u32 own3) -> short8 {
        const u32 sendA = hi ? own0 : own2;
        const u32 sendB = hi ? own1 : own3;
        const u32 recvA = (u32)__shfl_xor((int)sendA, 32);
        const u32 recvB = (u32)__shfl_xor((int)sendB, 32);
        u32x4 bw;
        bw[0] = hi ? recvA : own0;
        bw[1] = hi ? recvB : own1;
        bw[2] = hi ? own2 : recvA;
        bw[3] = hi ? own3 : recvB;
        return __builtin_bit_cast(short8, bw);
    };

    stage_load(0);
    stage_write(0);
    __syncthreads();

#pragma unroll 2
    for (int tt = 0; tt < NJT; ++tt) {
        const int cur = tt & 1;
        const int nxt = cur ^ 1;
        const bool pre = (tt + 1 < NJT);
        if (pre) stage_load(tt + 1);    // issue global loads early (T14)

        __builtin_amdgcn_s_setprio(1);
        f32x16 s0 = qkt32(cur, 0);
        f32x16 s1 = qkt32(cur, 1);
        __builtin_amdgcn_s_setprio(0);

        // ---- softmax numerators, m = 0 fixed; scores pre-scaled by log2e ----
#pragma unroll
        for (int i = 0; i < 16; i++) {
            s0[i] = exp2f(s0[i]);
            s1[i] = exp2f(s1[i]);
        }
        float psum = 0.f;
#pragma unroll
        for (int i = 0; i < 16; i++) psum += s0[i] + s1[i];
        l_r += psum;

        short8 pf0 = mkfrag(pk_bf16(s0[0],  s0[1]),  pk_bf16(s0[2],  s0[3]),
                            pk_bf16(s0[4],  s0[5]),  pk_bf16(s0[6],  s0[7]));
        short8 pf1 = mkfrag(pk_bf16(s0[8],  s0[9]),  pk_bf16(s0[10], s0[11]),
                            pk_bf16(s0[12], s0[13]), pk_bf16(s0[14], s0[15]));
        short8 pf2 = mkfrag(pk_bf16(s1[0],  s1[1]),  pk_bf16(s1[2],  s1[3]),
                            pk_bf16(s1[4],  s1[5]),  pk_bf16(s1[6],  s1[7]));
        short8 pf3 = mkfrag(pk_bf16(s1[8],  s1[9]),  pk_bf16(s1[10], s1[11]),
                            pk_bf16(s1[12], s1[13]), pk_bf16(s1[14], s1[15]));

        // ---- PV: 4 c-tiles x 4 j-groups (r11-verified read swizzle) ----
        __builtin_amdgcn_s_setprio(1);
#pragma unroll
        for (int jg = 0; jg < 4; jg++) {
            const int ch = jg * 2 + hi;
            const short8 pf = (jg == 0) ? pf0 : (jg == 1) ? pf1 : (jg == 2) ? pf2 : pf3;
#define PV_CT(CT, ACC)                                                        \
            {                                                                 \
                const int row = CT * 32 + q5;                                 \
                const int sw  = (row >> 2) & 3;                               \
                const int ph  = ((ch & 4) | ((ch ^ sw) & 3)) * 8;             \
                short8 vb = *(const short8*)&lv[cur][row][ph];                \
                ACC = __builtin_amdgcn_mfma_f32_32x32x16_bf16(vb, pf, ACC, 0, 0, 0); \
            }
            PV_CT(0, acc0)
            PV_CT(1, acc1)
            PV_CT(2, acc2)
            PV_CT(3, acc3)
#undef PV_CT
        }
        __builtin_amdgcn_s_setprio(0);

        if (pre) stage_write(nxt);
        __syncthreads();
    }
    // lv is block-wide dead after the final barrier; lt (aliased) safe.

    // ---- l: reduce over hi halves, store (h==0 blocks only) ----
    l_r += __shfl_xor(l_r, 32);
    if (h == 0 && l < 32)
        pl[((size_t)((b * 2 + js) * 32 + qb)) * 128 + w * 32 + q5] = l_r;

    // ---- write partial acc as bf16 via per-wave lt transpose ----
    const size_t tile = (size_t)(((b * 2 + h) * 2 + js) * 32 + qb);
    const int r2 = l >> 1;
    const int qc = (l & 1) * 16;
#pragma unroll
    for (int ct = 0; ct < 4; ct++) {
        const f32x16 a = (ct == 0) ? acc0 : (ct == 1) ? acc1 : (ct == 2) ? acc2 : acc3;
#pragma unroll
        for (int reg = 0; reg < 16; reg++) {
            const int crow = (reg & 3) + 8 * (reg >> 2) + 4 * hi;
            lt[w][crow][q5] = a[reg];
        }
        // lt[w] wave-private; DS ops in-order per wave
        const int c_local = ct * 32 + r2;
        const size_t base = (tile * 128 + c_local) * 128 + w * 32 + qc;
        u32x4 pk0, pk1;
#pragma unroll
        for (int i = 0; i < 4; i++)
            pk0[i] = pk_bf16(lt[w][r2][qc + 2 * i], lt[w][r2][qc + 2 * i + 1]);
#pragma unroll
        for (int i = 0; i < 4; i++)
            pk1[i] = pk_bf16(lt[w][r2][qc + 8 + 2 * i], lt[w][r2][qc + 8 + 2 * i + 1]);
        *(u32x4*)&pacc[base]     = pk0;
        *(u32x4*)&pacc[base + 8] = pk1;
    }
}

// ---------------------------------------------------------------------------
// Combine: out[b][c][i] = (accA + accB) / (lA + lB) + x.  Memory-bound.
// pacc is bf16; 8 outputs per thread-rep.
// ---------------------------------------------------------------------------
__global__ __launch_bounds__(256)
void attn_combine(const u16* __restrict__ pacc, const float* __restrict__ pl,
                  const float* __restrict__ x, float* __restrict__ out) {
    const int g = blockIdx.x * 256 + threadIdx.x;     // grid 512 -> 131072 thr
#pragma unroll
    for (int rep = 0; rep < 4; rep++) {
        const int f = g + rep * 131072;               // 8-q unit, 0..524287
        const int il8 = f & 15;                       // q-octet within 128
        const int qb  = (f >> 4) & 31;
        const int c   = (f >> 9) & 255;
        const int b   = f >> 17;
        const int h   = c >> 7;
        const int cl7 = c & 127;
        const size_t t0 = (size_t)(((b * 2 + h) * 2 + 0) * 32 + qb);
        const size_t t1 = t0 + 32;                    // js = 1
        const u16x8 a0 = *(const u16x8*)&pacc[(t0 * 128 + cl7) * 128 + il8 * 8];
        const u16x8 a1 = *(const u16x8*)&pacc[(t1 * 128 + cl7) * 128 + il8 * 8];
        const size_t lb0 = ((size_t)((b * 2 + 0) * 32 + qb)) * 128 + il8 * 8;
        const size_t lb1 = ((size_t)((b * 2 + 1) * 32 + qb)) * 128 + il8 * 8;
        const f32x4 l00 = *(const f32x4*)&pl[lb0];
        const f32x4 l01 = *(const f32x4*)&pl[lb0 + 4];
        const f32x4 l10 = *(const f32x4*)&pl[lb1];
        const f32x4 l11 = *(const f32x4*)&pl[lb1 + 4];
        const size_t ox = ((size_t)(b * 256 + c)) * 4096 + qb * 128 + il8 * 8;
        const f32x4 x0 = *(const f32x4*)&x[ox];
        const f32x4 x1 = *(const f32x4*)&x[ox + 4];
        f32x4 o0, o1;
#pragma unroll
        for (int i = 0; i < 4; i++) {
            o0[i] = (bf2f(a0[i]) + bf2f(a1[i])) / (l00[i] + l10[i]) + x0[i];
            o1[i] = (bf2f(a0[4 + i]) + bf2f(a1[4 + i])) / (l01[i] + l11[i]) + x1[i];
        }
        *(f32x4*)&out[ox]     = o0;
        *(f32x4*)&out[ox + 4] = o1;
    }
}

// ---------------------------------------------------------------------------
extern "C" void kernel_launch(void* const* d_in, const int* in_sizes, int n_in,
                              void* d_out, int out_size, void* d_ws, size_t ws_size,
                              hipStream_t stream) {
    const float* x  = (const float*)d_in[0];
    const float* Wq = (const float*)d_in[1];
    const float* bq = (const float*)d_in[2];
    const float* Wk = (const float*)d_in[3];
    const float* bk = (const float*)d_in[4];
    const float* Wv = (const float*)d_in[5];
    const float* bv = (const float*)d_in[6];
    float* out = (float*)d_out;

    u16* qhi = (u16*)d_ws;                              // [4][4096][32]
    u16* qlo = qhi + (size_t)4 * NTOK * 32;
    u16* khi = qlo + (size_t)4 * NTOK * 32;
    u16* klo = khi + (size_t)4 * NTOK * 32;
    u16* vbf = klo + (size_t)4 * NTOK * 32;             // [4][256][4096]
    u16* whi = vbf + (size_t)4 * CDIM * NTOK;           // [320][256]
    u16* wlo = whi + (size_t)320 * 256;
    u16* pacc = wlo + (size_t)320 * 256;                // [512][128][128] bf16
    float* pl = (float*)(pacc + (size_t)512 * 128 * 128);  // [256][128] f32

    wconv<<<dim3(320), 256, 0, stream>>>(Wq, Wk, Wv, whi, wlo);
    proj_fused<<<dim3(64, 4), 256, 0, stream>>>(x, whi, wlo, bq, bk, bv,
                                                qhi, qlo, khi, klo, vbf);
    attn_part<<<dim3(512), 256, 0, stream>>>(qhi, qlo, khi, klo, vbf, pacc, pl);
    attn_combine<<<dim3(512), 256, 0, stream>>>(pacc, pl, x, out);
}